// Round 16
// baseline (79.725 us; speedup 1.0000x reference)
//
#include <hip/hip_runtime.h>

#define NUM_CLASSES 80
constexpr int Bn = 8;
constexpr int Gn = 128;
constexpr int An = 131072;

constexpr int TB   = 256;   // threads per block (4 waves)
constexpr int BBLK = 512;   // anchors per block (2 per thread)
constexpr int NST  = (BBLK * 20) / TB;   // 40 zero-stores per thread
constexpr int GPB  = 3;     // g-iters per burst: 40*3 = 120 (+prologue+tail)

// out layout: cls (B,A,80) | reg (B,A,4) | states (B,A)
constexpr size_t CLS_OFF = 0;
constexpr size_t REG_OFF = (size_t)Bn * An * NUM_CLASSES;
constexpr size_t ST_OFF  = REG_OFF + (size_t)Bn * An * 4;

__global__ __launch_bounds__(TB, 4) void targets_kernel(
    const float* __restrict__ ann,      // (B,G,5) x1,y1,x2,y2,label
    const float* __restrict__ anchors,  // (A,4)
    float* __restrict__ out)
{
#pragma clang fp contract(off)
    const int tid  = threadIdx.x;
    const int b    = blockIdx.y;
    const int base = blockIdx.x * BBLK;
    const int ph   = b;                 // per-CU phase stagger: 0..7 g-iters

    __shared__ float4 sbox[Gn];
    __shared__ float  sarea[Gn];
    __shared__ float  slabel[Gn];
    __shared__ int    slab[BBLK];

    if (tid < Gn) {
        const float* p = ann + ((size_t)b * Gn + tid) * 5;
        const float x1 = p[0], y1 = p[1], x2 = p[2], y2 = p[3];
        sbox[tid]   = make_float4(x1, y1, x2, y2);
        sarea[tid]  = (x2 - x1) * (y2 - y1);   // ref op order
        slabel[tid] = p[4];
    }

    // anchor loads issued before the barrier (in flight across it)
    const int a = base + tid * 2;
    const float4 av0 = *reinterpret_cast<const float4*>(anchors + (size_t)a * 4);
    const float4 av1 = *reinterpret_cast<const float4*>(anchors + (size_t)a * 4 + 4);

    __syncthreads();   // staging visible

    float4* cls_blk = reinterpret_cast<float4*>(
        out + CLS_OFF + ((size_t)b * An + base) * NUM_CLASSES);
    const float4 z = make_float4(0.f, 0.f, 0.f, 0.f);

    const float ax1[2] = { av0.x, av1.x };
    const float ay1[2] = { av0.y, av1.y };
    const float ax2[2] = { av0.z, av1.z };
    const float ay2[2] = { av0.w, av1.w };
    float wa[2], ha[2], area_a[2], interB[2], uniB[2];
    int besti[2];
    #pragma unroll
    for (int j = 0; j < 2; ++j) {
        wa[j] = ax2[j] - ax1[j];
        ha[j] = ay2[j] - ay1[j];
        area_a[j] = wa[j] * ha[j];      // ref op order
        interB[j] = -1.0f;              // sentinel: g=0 wins first compare
        uniB[j]   = 1.0f;
        besti[j]  = 0;
    }

    auto g_iter = [&](int g) {
        const float4 bv = sbox[g];        // broadcast ds_read_b128
        const float area_b = sarea[g];    // broadcast ds_read_b32
        #pragma unroll
        for (int j = 0; j < 2; ++j) {
            float iw = fminf(ax2[j], bv.z) - fmaxf(ax1[j], bv.x);
            iw = fmaxf(iw, 0.0f);
            float ih = fminf(ay2[j], bv.w) - fmaxf(ay1[j], bv.y);
            ih = fmaxf(ih, 0.0f);
            const float inter = iw * ih;
            const float uni = (area_a[j] + area_b) - inter;  // ref order, > 0
            // iou_g > iou_best <=> inter*uniB > interB*uni (both unions > 0)
            const bool upd = (inter * uniB[j]) > (interB[j] * uni);
            interB[j] = upd ? inter : interB[j];
            uniB[j]   = upd ? uni   : uniB[j];
            besti[j]  = upd ? g     : besti[j];
        }
    };

    // finest-grain interleave, CORRECT budget this time:
    //   prologue: ph g-iters (ph = 0..7)
    //   bursts:   40 x {1 zero-store, 3 g-iters} = 120 g-iters
    //   tail:     8 - ph g-iters
    // total = ph + 120 + (8-ph) = 128; g strictly sequential 0..127.
    // Max g touched inside bursts = ph + 119 <= 126 (in bounds).
    int g = 0;
    for (; g < ph; ++g) g_iter(g);      // rolled, <=7 iters

    #pragma unroll
    for (int i = 0; i < NST; ++i) {
        cls_blk[tid + i * TB] = z;      // 1 data-independent zero-store
        #pragma unroll
        for (int k = 0; k < GPB; ++k) g_iter(g + k);
        g += GPB;
    }
    for (; g < Gn; ++g) g_iter(g);      // rolled tail, 1..8 iters

    // states (float2: this thread's 2 anchors are adjacent)
    float st[2];
    #pragma unroll
    for (int j = 0; j < 2; ++j) {
        const float best = interB[j] / fmaxf(uniB[j], 1e-8f);  // exact ref div
        st[j] = (best >= 0.5f) ? 1.0f : ((best < 0.4f) ? 0.0f : -1.0f);
    }
    *reinterpret_cast<float2*>(out + ST_OFF + (size_t)b * An + a) =
        make_float2(st[0], st[1]);

    #pragma unroll
    for (int j = 0; j < 2; ++j) {
        const float4 gt = sbox[besti[j]];
        float4 rv;
        rv.x = ((gt.x - ax1[j]) / wa[j]) / 0.2f;
        rv.y = ((gt.y - ay1[j]) / ha[j]) / 0.2f;
        rv.z = ((gt.z - ax2[j]) / wa[j]) / 0.2f;
        rv.w = ((gt.w - ay2[j]) / ha[j]) / 0.2f;
        *reinterpret_cast<float4*>(out + REG_OFF + ((size_t)b * An + a + j) * 4) = rv;
        slab[tid * 2 + j] = (st[j] == 1.0f) ? (int)slabel[besti[j]] : -1;
    }

    // barrier: slab visible; vmcnt(0) drain orders zero-stores before patches
    __syncthreads();

    // sparse patch: one dword per positive anchor (lines still L2-resident)
    #pragma unroll
    for (int k = tid; k < BBLK; k += TB) {
        const int lab = slab[k];
        if (lab >= 0)
            out[CLS_OFF + ((size_t)b * An + base + k) * NUM_CLASSES + lab] = 1.0f;
    }
}

extern "C" void kernel_launch(void* const* d_in, const int* in_sizes, int n_in,
                              void* d_out, int out_size, void* d_ws, size_t ws_size,
                              hipStream_t stream) {
    const float* ann     = (const float*)d_in[0];   // (8,128,5)
    const float* anchors = (const float*)d_in[1];   // (131072,4)
    float* out = (float*)d_out;

    dim3 grid(An / BBLK, Bn, 1);   // 256 x 8 = 2048 blocks (4 resident / CU)
    dim3 block(TB, 1, 1);
    targets_kernel<<<grid, block, 0, stream>>>(ann, anchors, out);
}